// Round 22
// baseline (101.829 us; speedup 1.0000x reference)
//
#include <hip/hip_runtime.h>
#include <hip/hip_bf16.h>
#include <stdint.h>

// Problem constants
#define B_  2
#define T_  2048
#define E_  1024
#define H_  16
#define D_  64
#define BH_ 32   // B_*H_

typedef unsigned short ushort_t;
typedef __attribute__((ext_vector_type(8))) short bfrag;   // 8 bf16 (4 VGPRs) MFMA A/B operand
typedef __attribute__((ext_vector_type(4))) short s16x4;   // 4 bf16 (8B)
typedef __attribute__((ext_vector_type(4))) float f32x4;   // MFMA C/D

__device__ __forceinline__ ushort_t f2b(float f) {  // fp32 -> bf16 (RTNE)
    uint32_t u = __builtin_bit_cast(uint32_t, f);
    u += 0x7fffu + ((u >> 16) & 1u);
    return (ushort_t)(u >> 16);
}

#if defined(__has_builtin)
#if __has_builtin(__builtin_amdgcn_exp2f)
#define EXP2(x) __builtin_amdgcn_exp2f(x)
#endif
#endif
#ifndef EXP2
__device__ __forceinline__ float hexp2_(float x) {
    float r;
    asm volatile("v_exp_f32 %0, %1\n\ts_nop 1" : "=v"(r) : "v"(x));
    return r;
}
#define EXP2(x) hexp2_(x)
#endif

__device__ __forceinline__ uint32_t cvtpk_bf16(float lo, float hi) {
    uint32_t r;
    asm("v_cvt_pk_bf16_f32 %0, %1, %2" : "=v"(r) : "v"(lo), "v"(hi));
    return r;
}

typedef const __attribute__((address_space(1))) uint8_t* gas_t;
typedef __attribute__((address_space(3))) uint8_t* las_t;
__device__ __forceinline__ void gload_lds16(const void* g, void* l) {
    // async global->LDS, 16B/lane; LDS dest = wave-uniform base + lane*16; global src per-lane
    __builtin_amdgcn_global_load_lds((gas_t)g, (las_t)l, 16, 0, 0);
}
__device__ __forceinline__ void drain_vmem() {
    asm volatile("s_waitcnt vmcnt(0)" ::: "memory");
    __builtin_amdgcn_sched_barrier(0);
}

// ---------------- fused prep: rope table | cast x | transpose w_qkv | transpose w_out ----------------
__global__ __launch_bounds__(256) void prep_kernel(const float* __restrict__ x, const float* __restrict__ w_qkv,
                                                   const float* __restrict__ w_out, ushort_t* __restrict__ xb,
                                                   ushort_t* __restrict__ wqkvT, ushort_t* __restrict__ woutT,
                                                   float2* __restrict__ cstab) {
    __shared__ float tile[32][36];
    int blk = blockIdx.x, tid = threadIdx.x;
    if (blk < 256) {
        int id = blk * 256 + tid;   // 65536
        int j = id & 31, t = id >> 5;
        float ang = (float)t * expf(-(float)j * 0.2878231366242558f);  // ln(10000)/32
        float s, c;
        sincosf(ang, &s, &c);
        cstab[id] = make_float2(c, s);
    } else if (blk < 2304) {
        int i = ((blk - 256) * 256 + tid) * 8;
        float4 a = *(const float4*)(x + i);
        float4 b = *(const float4*)(x + i + 4);
        ushort_t r[8] = {f2b(a.x), f2b(a.y), f2b(a.z), f2b(a.w), f2b(b.x), f2b(b.y), f2b(b.z), f2b(b.w)};
        *(uint4*)(xb + i) = *(const uint4*)r;
    } else {
        const float* in;
        ushort_t* out;
        int R, C, bx, by;
        if (blk < 5376) { in = w_qkv; out = wqkvT; R = 1024; C = 3072; int t = blk - 2304; bx = t % 96; by = t / 96; }
        else            { in = w_out; out = woutT; R = 1024; C = 1024; int t = blk - 5376; bx = t % 32; by = t / 32; }
        int c0 = bx * 32, r0 = by * 32;
        int ty = tid >> 3, tx = tid & 7;
        float4 v = *(const float4*)&in[(size_t)(r0 + ty) * C + c0 + tx * 4];
        *(float4*)&tile[ty][tx * 4] = v;
        __syncthreads();
        int cc = tid & 31, rq = tid >> 5;
        float t0 = tile[rq * 4 + 0][cc], t1 = tile[rq * 4 + 1][cc];
        float t2 = tile[rq * 4 + 2][cc], t3 = tile[rq * 4 + 3][cc];
        uint2 w;
        w.x = cvtpk_bf16(t0, t1);
        w.y = cvtpk_bf16(t2, t3);
        *(uint2*)&out[(size_t)(c0 + cc) * R + r0 + rq * 4] = w;
    }
}

// ---------------- GEMM1: qkv = x @ w_qkv + b, fused RoPE on q,k ----------------
// Tile 128x128, BK=128 (8 iters), XOR-swizzled single-buffer LDS (64 KB). (R20-proven, 45.2us)
__global__ __launch_bounds__(256) void gemm_qkv_kernel(const ushort_t* __restrict__ A, const ushort_t* __restrict__ Bt,
                                                       const float* __restrict__ bias, const float2* __restrict__ cstab,
                                                       ushort_t* __restrict__ qw, ushort_t* __restrict__ kw,
                                                       ushort_t* __restrict__ vw) {
    const int K = 1024;
    __shared__ ushort_t As[128 * 128];   // 32 KB
    __shared__ ushort_t Bs[128 * 128];   // 32 KB
    int tid = threadIdx.x, lane = tid & 63, wid = tid >> 6;
    int lm = lane & 15, lg = lane >> 4;
    int bid = blockIdx.x;               // 768 blocks
    int xcd = bid & 7, idx = bid >> 3;  // idx in [0,96)
    int bm = xcd * 4 + idx / 24;
    int bn = idx % 24;
    int wm = wid >> 1, wn = wid & 1;

    int cbase = bn * 128 + wn * 64;     // 64-col band = one head's D
    bool qk = (cbase < 2048);

    f32x4 acc[4][4] = {};
    const ushort_t* ag = A + (size_t)bm * 128 * K;
    const ushort_t* bg = Bt + (size_t)bn * 128 * K;

    for (int kt = 0; kt < K / 128; ++kt) {
        __syncthreads();
#pragma unroll
        for (int c = 0; c < 8; ++c) {
            int G = c * 256 + tid;                      // granule id 0..2047
            int rr = G >> 4;                            // tile row 0..127
            int slot = G & 15;                          // LDS slot 0..15
            int gs = (slot & 8) | ((slot & 7) ^ (rr & 7));
            gload_lds16(ag + (size_t)rr * K + kt * 128 + gs * 8, As + (c * 256 + wid * 64) * 8);
            gload_lds16(bg + (size_t)rr * K + kt * 128 + gs * 8, Bs + (c * 256 + wid * 64) * 8);
        }
        __syncthreads();   // compiler drains vmcnt before barrier
#pragma unroll
        for (int kk = 0; kk < 4; ++kk) {
            bfrag a[4], b[4];
#pragma unroll
            for (int mi = 0; mi < 4; ++mi) {
                int row = wm * 64 + mi * 16 + lm;
                int slot = kk * 4 + lg;
                int phys = (slot & 8) | ((slot & 7) ^ (lm & 7));
                a[mi] = *(const bfrag*)&As[row * 128 + phys * 8];
            }
#pragma unroll
            for (int ni = 0; ni < 4; ++ni) {
                int row = wn * 64 + ni * 16 + lm;
                int slot = kk * 4 + lg;
                int phys = (slot & 8) | ((slot & 7) ^ (lm & 7));
                b[ni] = *(const bfrag*)&Bs[row * 128 + phys * 8];
            }
            if (qk) {
#pragma unroll
                for (int mi = 0; mi < 4; ++mi)
#pragma unroll
                    for (int ni = 0; ni < 4; ++ni)
                        acc[mi][ni] = __builtin_amdgcn_mfma_f32_16x16x32_bf16(b[ni], a[mi], acc[mi][ni], 0, 0, 0);
            } else {
#pragma unroll
                for (int mi = 0; mi < 4; ++mi)
#pragma unroll
                    for (int ni = 0; ni < 4; ++ni)
                        acc[mi][ni] = __builtin_amdgcn_mfma_f32_16x16x32_bf16(a[mi], b[ni], acc[mi][ni], 0, 0, 0);
            }
        }
    }

    int sel = cbase >> 10;                    // 0=q 1=k 2=v
    int h = (cbase & 1023) >> 6;
    if (qk) {
        // swapped layout: acc[mi][ni][i] at (d = ni*16+lg*4+i, t-row = mi*16+lm)
        ushort_t* dst = sel ? kw : qw;
        float scale = sel ? 1.0f : 0.18033688011112042f;  // q: 1/sqrt(64) * log2(e)
        float4 bias4[4];
#pragma unroll
        for (int ni = 0; ni < 4; ++ni)
            bias4[ni] = *(const float4*)&bias[cbase + ni * 16 + lg * 4];
#pragma unroll
        for (int mi = 0; mi < 4; ++mi) {
            int r = bm * 128 + wm * 64 + mi * 16 + lm;
            int bb = r >> 11, t = r & (T_ - 1);
            size_t rowbase = ((size_t)(bb * H_ + h) * T_ + t) * D_;
#pragma unroll
            for (int nip = 0; nip < 2; ++nip) {
                const float4* cs2 = (const float4*)(cstab + t * 32 + nip * 16 + lg * 4);
                float4 ca = cs2[0], cb = cs2[1];   // (c0,s0,c1,s1),(c2,s2,c3,s3)
                float xl[4], xh[4];
#pragma unroll
                for (int i = 0; i < 4; ++i) {
                    xl[i] = acc[mi][nip][i]     + ((const float*)&bias4[nip])[i];
                    xh[i] = acc[mi][nip + 2][i] + ((const float*)&bias4[nip + 2])[i];
                }
                float rl0 = (xl[0] * ca.x - xh[0] * ca.y) * scale;
                float rl1 = (xl[1] * ca.z - xh[1] * ca.w) * scale;
                float rl2 = (xl[2] * cb.x - xh[2] * cb.y) * scale;
                float rl3 = (xl[3] * cb.z - xh[3] * cb.w) * scale;
                float rh0 = (xh[0] * ca.x + xl[0] * ca.y) * scale;
                float rh1 = (xh[1] * ca.z + xl[1] * ca.w) * scale;
                float rh2 = (xh[2] * cb.x + xl[2] * cb.y) * scale;
                float rh3 = (xh[3] * cb.z + xl[3] * cb.w) * scale;
                uint2 wlo, whi;
                wlo.x = cvtpk_bf16(rl0, rl1); wlo.y = cvtpk_bf16(rl2, rl3);
                whi.x = cvtpk_bf16(rh0, rh1); whi.y = cvtpk_bf16(rh2, rh3);
                *(uint2*)&dst[rowbase + nip * 16 + lg * 4]      = wlo;
                *(uint2*)&dst[rowbase + 32 + nip * 16 + lg * 4] = whi;
            }
        }
    } else {
        // normal layout: acc[mi][ni][i] at (t-row = mi*16+lg*4+i, d = ni*16+lm)
        float bb4[4];
#pragma unroll
        for (int ni = 0; ni < 4; ++ni) bb4[ni] = bias[cbase + ni * 16 + lm];
#pragma unroll
        for (int ni = 0; ni < 4; ++ni) {
            int d = ni * 16 + lm;
#pragma unroll
            for (int mi = 0; mi < 4; ++mi) {
                int r = bm * 128 + wm * 64 + mi * 16 + lg * 4;
                int bb = r >> 11, tq = r & (T_ - 1);
                uint2 w;
                w.x = cvtpk_bf16(acc[mi][ni][0] + bb4[ni], acc[mi][ni][1] + bb4[ni]);
                w.y = cvtpk_bf16(acc[mi][ni][2] + bb4[ni], acc[mi][ni][3] + bb4[ni]);
                *(uint2*)&vw[((size_t)(bb * H_ + h) * D_ + d) * T_ + tq] = w;
            }
        }
    }
}

// ---------------- causal flash attention: LDS-shared K/V tiles, 4 waves x 32 Q-rows ----------------
// KVBLK=256 staged once (64 KB), FOUR 64-key quarters (R19-proven). T5: setprio(1) around
// the MFMA clusters — 2 independent blocks/CU at different phases, attn case (m191: +4-7%).
__global__ __launch_bounds__(256, 2) void flash_kernel(const ushort_t* __restrict__ q, const ushort_t* __restrict__ k,
                                                       const ushort_t* __restrict__ vt, ushort_t* __restrict__ o) {
    __shared__ ushort_t smemK[256 * 64];   // 32 KB
    __shared__ ushort_t smemV[64 * 256];   // 32 KB
    int tid = threadIdx.x, lane = tid & 63, wid = tid >> 6;
    int lm = lane & 15, lg = lane >> 4;
    int x = blockIdx.x & 7, r = blockIdx.x >> 3;   // x = XCD
    int half = r >> 5, idx = r & 31;
    int bh = x * 4 + (idx & 3);             // XCD x owns bh 4x..4x+3
    int jq = idx >> 2;
    int j = half ? jq : 15 - jq;            // q-block (128 rows); long (j=15) first
    int q0w = j * 128 + wid * 32;           // this wave's 32 rows
    int b = bh >> 4, h = bh & 15;
    int nt = (j >> 1) + 1;                  // 256-key tiles

    const ushort_t* qb = q + (size_t)bh * T_ * D_;
    const ushort_t* kb = k + (size_t)bh * T_ * D_;
    const ushort_t* vb = vt + (size_t)bh * D_ * T_;

    bfrag aq[2][2];
#pragma unroll
    for (int s = 0; s < 2; ++s)
#pragma unroll
        for (int hh = 0; hh < 2; ++hh)
            aq[s][hh] = *(const bfrag*)(qb + (size_t)(q0w + s * 16 + lm) * D_ + hh * 32 + lg * 8);

    f32x4 acc[2][4] = {};
    float lsum[2] = {0.f, 0.f};

    for (int t = 0; t < nt; ++t) {
        int k0 = t * 256;
        __syncthreads();
#pragma unroll
        for (int c = 0; c < 8; ++c) {
            int G = c * 256 + tid;                            // granule 0..2047
            int rrk = G >> 3, gk = (G & 7) ^ (rrk & 7);       // K: 256 rows x 8 granules
            gload_lds16(kb + (size_t)(k0 + rrk) * D_ + gk * 8, smemK + (c * 256 + wid * 64) * 8);
            int rrv = G >> 5, gv = (G & 31) ^ (rrv & 7);      // V: 64 rows x 32 granules
            gload_lds16(vb + (size_t)rrv * T_ + k0 + gv * 8, smemV + (c * 256 + wid * 64) * 8);
        }
        drain_vmem();
        __syncthreads();

        for (int h1 = 0; h1 < 4; ++h1) {
            int hk0 = k0 + h1 * 64;
            if (hk0 > q0w + 31) continue;   // causally dead quarter for this wave
            bfrag ka[4][2];
#pragma unroll
            for (int sb = 0; sb < 4; ++sb)
#pragma unroll
                for (int hh = 0; hh < 2; ++hh) {
                    int krr = h1 * 64 + sb * 16 + lm;
                    int gr = (hh * 4 + lg) ^ (krr & 7);
                    ka[sb][hh] = *(const bfrag*)&smemK[krr * 64 + gr * 8];
                }
            s16x4 vq[4][4];
#pragma unroll
            for (int qq = 0; qq < 4; ++qq)
#pragma unroll
                for (int db = 0; db < 4; ++db) {
                    int rr = db * 16 + lm;
                    int g = h1 * 8 + qq * 2 + (lg >> 1);
                    int p = g ^ (rr & 7);
                    vq[qq][db] = *(const s16x4*)&smemV[rr * 256 + p * 8 + (lg & 1) * 4];
                }
            f32x4 st[2][4];
            __builtin_amdgcn_s_setprio(1);
#pragma unroll
            for (int s = 0; s < 2; ++s)
#pragma unroll
                for (int sb = 0; sb < 4; ++sb) {
                    f32x4 z = {};
                    z = __builtin_amdgcn_mfma_f32_16x16x32_bf16(ka[sb][0], aq[s][0], z, 0, 0, 0);
                    st[s][sb] = __builtin_amdgcn_mfma_f32_16x16x32_bf16(ka[sb][1], aq[s][1], z, 0, 0, 0);
                }
            __builtin_amdgcn_s_setprio(0);
            if (hk0 + 63 > q0w) {
#pragma unroll
                for (int s = 0; s < 2; ++s)
#pragma unroll
                    for (int sb = 0; sb < 4; ++sb)
#pragma unroll
                        for (int i = 0; i < 4; ++i)
                            if (hk0 + sb * 16 + lg * 4 + i > q0w + s * 16 + lm) st[s][sb][i] = -1e30f;
            }
#pragma unroll
            for (int s = 0; s < 2; ++s) {
                float pv[4][4];
#pragma unroll
                for (int sb = 0; sb < 4; ++sb)
#pragma unroll
                    for (int i = 0; i < 4; ++i)
                        pv[sb][i] = EXP2(st[s][sb][i]);
                lsum[s] += ((pv[0][0] + pv[0][1]) + (pv[0][2] + pv[0][3])) +
                           ((pv[1][0] + pv[1][1]) + (pv[1][2] + pv[1][3])) +
                           ((pv[2][0] + pv[2][1]) + (pv[2][2] + pv[2][3])) +
                           ((pv[3][0] + pv[3][1]) + (pv[3][2] + pv[3][3]));
                uint4 u0, u1;
                u0.x = cvtpk_bf16(pv[0][0], pv[0][1]);
                u0.y = cvtpk_bf16(pv[0][2], pv[0][3]);
                u0.z = cvtpk_bf16(pv[1][0], pv[1][1]);
                u0.w = cvtpk_bf16(pv[1][2], pv[1][3]);
                u1.x = cvtpk_bf16(pv[2][0], pv[2][1]);
                u1.y = cvtpk_bf16(pv[2][2], pv[2][3]);
                u1.z = cvtpk_bf16(pv[3][0], pv[3][1]);
                u1.w = cvtpk_bf16(pv[3][2], pv[3][3]);
                bfrag pf0 = __builtin_bit_cast(bfrag, u0);
                bfrag pf1 = __builtin_bit_cast(bfrag, u1);
                __builtin_amdgcn_s_setprio(1);
#pragma unroll
                for (int db = 0; db < 4; ++db) {
                    bfrag va01 = __builtin_shufflevector(vq[0][db], vq[1][db], 0, 1, 2, 3, 4, 5, 6, 7);
                    bfrag va23 = __builtin_shufflevector(vq[2][db], vq[3][db], 0, 1, 2, 3, 4, 5, 6, 7);
                    acc[s][db] = __builtin_amdgcn_mfma_f32_16x16x32_bf16(va01, pf0, acc[s][db], 0, 0, 0);
                    acc[s][db] = __builtin_amdgcn_mfma_f32_16x16x32_bf16(va23, pf1, acc[s][db], 0, 0, 0);
                }
                __builtin_amdgcn_s_setprio(0);
            }
        }
    }

#pragma unroll
    for (int s = 0; s < 2; ++s) {
        float lM = lsum[s];
        lM += __shfl_xor(lM, 16);
        lM += __shfl_xor(lM, 32);
        float inv = 1.0f / lM;
        int tq = q0w + s * 16 + lm;
        size_t ro = ((size_t)b * T_ + tq) * E_ + h * D_;
#pragma unroll
        for (int db = 0; db < 4; ++db) {
            uint2 w;
            w.x = cvtpk_bf16(acc[s][db][0] * inv, acc[s][db][1] * inv);
            w.y = cvtpk_bf16(acc[s][db][2] * inv, acc[s][db][3] * inv);
            *(uint2*)(o + ro + db * 16 + lg * 4) = w;
        }
    }
}

// ---------------- GEMM2: out = ao @ w_out + b_out (fp32 out) ----------------
// Tile 128x64, BK=128 (8 iters), XOR-swizzled SINGLE-buffer LDS (48 KB). (R21-proven)
__global__ __launch_bounds__(256) void gemm_out_kernel(const ushort_t* __restrict__ A, const ushort_t* __restrict__ Bt,
                                                       const float* __restrict__ bias, float* __restrict__ out) {
    const int K = 1024;
    __shared__ ushort_t As[128 * 128];   // 32 KB
    __shared__ ushort_t Bs[64 * 128];    // 16 KB
    int tid = threadIdx.x, lane = tid & 63, wid = tid >> 6;
    int lm = lane & 15, lg = lane >> 4;
    int bid = blockIdx.x;               // 512 blocks
    int xcd = bid & 7, idx = bid >> 3;  // idx in [0,64)
    int bm = xcd * 4 + idx / 16;
    int bn = idx % 16;

    f32x4 acc[2][4] = {};
    const ushort_t* ag = A + (size_t)bm * 128 * K;
    const ushort_t* bg = Bt + (size_t)bn * 64 * K;

    for (int kt = 0; kt < K / 128; ++kt) {
        __syncthreads();
#pragma unroll
        for (int c = 0; c < 8; ++c) {
            int G = c * 256 + tid;                      // granule 0..2047
            int rr = G >> 4;                            // tile row 0..127
            int slot = G & 15;
            int gs = (slot & 8) | ((slot & 7) ^ (rr & 7));
            gload_lds16(ag + (size_t)rr * K + kt * 128 + gs * 8, As + (c * 256 + wid * 64) * 8);
        }
#pragma unroll
        for (int c = 0; c < 4; ++c) {
            int G = c * 256 + tid;                      // granule 0..1023
            int rr = G >> 4;                            // tile row 0..63
            int slot = G & 15;
            int gs = (slot & 8) | ((slot & 7) ^ (rr & 7));
            gload_lds16(bg + (size_t)rr * K + kt * 128 + gs * 8, Bs + (c * 256 + wid * 64) * 8);
        }
        __syncthreads();   // compiler drains vmcnt before barrier
#pragma unroll
        for (int kk = 0; kk < 4; ++kk) {
            bfrag a[2], b[4];
#pragma unroll
            for (int mi = 0; mi < 2; ++mi) {
                int row = wid * 32 + mi * 16 + lm;
                int slot = kk * 4 + lg;
                int phys = (slot & 8) | ((slot & 7) ^ (lm & 7));
                a[mi] = *(const bfrag*)&As[row * 128 + phys * 8];
            }
#pragma unroll
            for (int ni = 0; ni < 4; ++ni) {
                int row = ni * 16 + lm;
                int slot = kk * 4 + lg;
                int phys = (slot & 8) | ((slot & 7) ^ (lm & 7));
                b[ni] = *(const bfrag*)&Bs[row * 128 + phys * 8];
            }
#pragma unroll
            for (int mi = 0; mi < 2; ++mi)
#pragma unroll
                for (int ni = 0; ni < 4; ++ni)
                    acc[mi][ni] = __builtin_amdgcn_mfma_f32_16x16x32_bf16(a[mi], b[ni], acc[mi][ni], 0, 0, 0);
        }
    }

#pragma unroll
    for (int ni = 0; ni < 4; ++ni) {
        int c = bn * 64 + ni * 16 + lm;
        float bb = bias[c];
#pragma unroll
        for (int mi = 0; mi < 2; ++mi) {
#pragma unroll
            for (int i = 0; i < 4; ++i) {
                int r = bm * 128 + wid * 32 + mi * 16 + lg * 4 + i;
                out[(size_t)r * 1024 + c] = acc[mi][ni][i] + bb;
            }
        }
    }
}

extern "C" void kernel_launch(void* const* d_in, const int* in_sizes, int n_in,
                              void* d_out, int out_size, void* d_ws, size_t ws_size,
                              hipStream_t stream) {
    const float* x     = (const float*)d_in[0];
    const float* w_qkv = (const float*)d_in[1];
    const float* b_qkv = (const float*)d_in[2];
    const float* w_out = (const float*)d_in[3];
    const float* b_out = (const float*)d_in[4];
    float* out = (float*)d_out;

    ushort_t* ws    = (ushort_t*)d_ws;
    ushort_t* xb    = ws;                   // [4096][1024] bf16
    ushort_t* wqkvT = xb + 4194304;         // [3072][1024] bf16
    ushort_t* woutT = wqkvT + 3145728;      // [1024][1024] bf16
    ushort_t* qw    = woutT + 1048576;      // [BH][T][D]
    ushort_t* kw    = qw + 4194304;
    ushort_t* vw    = kw + 4194304;         // Vt: [BH][D][T]
    ushort_t* ao    = vw + 4194304;         // [4096][1024] bf16
    float2*   cstab = (float2*)(ao + 4194304);  // [2048][32] (cos,sin) = 512 KB

    prep_kernel<<<dim3(6400), 256, 0, stream>>>(x, w_qkv, w_out, xb, wqkvT, woutT, cstab);
    gemm_qkv_kernel<<<dim3(768), 256, 0, stream>>>(xb, wqkvT, b_qkv, cstab, qw, kw, vw);
    flash_kernel<<<dim3(512), 256, 0, stream>>>(qw, kw, vw, ao);
    gemm_out_kernel<<<dim3(512), 256, 0, stream>>>(ao, woutT, b_out, out);
}

// Round 23
// 99.257 us; speedup vs baseline: 1.0259x; 1.0259x over previous
//
#include <hip/hip_runtime.h>
#include <hip/hip_bf16.h>
#include <stdint.h>

// Problem constants
#define B_  2
#define T_  2048
#define E_  1024
#define H_  16
#define D_  64
#define BH_ 32   // B_*H_

typedef unsigned short ushort_t;
typedef __attribute__((ext_vector_type(8))) short bfrag;   // 8 bf16 (4 VGPRs) MFMA A/B operand
typedef __attribute__((ext_vector_type(4))) short s16x4;   // 4 bf16 (8B)
typedef __attribute__((ext_vector_type(4))) float f32x4;   // MFMA C/D

__device__ __forceinline__ ushort_t f2b(float f) {  // fp32 -> bf16 (RTNE)
    uint32_t u = __builtin_bit_cast(uint32_t, f);
    u += 0x7fffu + ((u >> 16) & 1u);
    return (ushort_t)(u >> 16);
}

#if defined(__has_builtin)
#if __has_builtin(__builtin_amdgcn_exp2f)
#define EXP2(x) __builtin_amdgcn_exp2f(x)
#endif
#endif
#ifndef EXP2
__device__ __forceinline__ float hexp2_(float x) {
    float r;
    asm volatile("v_exp_f32 %0, %1\n\ts_nop 1" : "=v"(r) : "v"(x));
    return r;
}
#define EXP2(x) hexp2_(x)
#endif

__device__ __forceinline__ uint32_t cvtpk_bf16(float lo, float hi) {
    uint32_t r;
    asm("v_cvt_pk_bf16_f32 %0, %1, %2" : "=v"(r) : "v"(lo), "v"(hi));
    return r;
}

typedef const __attribute__((address_space(1))) uint8_t* gas_t;
typedef __attribute__((address_space(3))) uint8_t* las_t;
__device__ __forceinline__ void gload_lds16(const void* g, void* l) {
    // async global->LDS, 16B/lane; LDS dest = wave-uniform base + lane*16; global src per-lane
    __builtin_amdgcn_global_load_lds((gas_t)g, (las_t)l, 16, 0, 0);
}
__device__ __forceinline__ void drain_vmem() {
    asm volatile("s_waitcnt vmcnt(0)" ::: "memory");
    __builtin_amdgcn_sched_barrier(0);
}

// ---------------- fused prep: rope table | cast x | transpose w_qkv | transpose w_out ----------------
__global__ __launch_bounds__(256) void prep_kernel(const float* __restrict__ x, const float* __restrict__ w_qkv,
                                                   const float* __restrict__ w_out, ushort_t* __restrict__ xb,
                                                   ushort_t* __restrict__ wqkvT, ushort_t* __restrict__ woutT,
                                                   float2* __restrict__ cstab) {
    __shared__ float tile[32][36];
    int blk = blockIdx.x, tid = threadIdx.x;
    if (blk < 256) {
        int id = blk * 256 + tid;   // 65536
        int j = id & 31, t = id >> 5;
        float ang = (float)t * expf(-(float)j * 0.2878231366242558f);  // ln(10000)/32
        float s, c;
        sincosf(ang, &s, &c);
        cstab[id] = make_float2(c, s);
    } else if (blk < 2304) {
        int i = ((blk - 256) * 256 + tid) * 8;
        float4 a = *(const float4*)(x + i);
        float4 b = *(const float4*)(x + i + 4);
        ushort_t r[8] = {f2b(a.x), f2b(a.y), f2b(a.z), f2b(a.w), f2b(b.x), f2b(b.y), f2b(b.z), f2b(b.w)};
        *(uint4*)(xb + i) = *(const uint4*)r;
    } else {
        const float* in;
        ushort_t* out;
        int R, C, bx, by;
        if (blk < 5376) { in = w_qkv; out = wqkvT; R = 1024; C = 3072; int t = blk - 2304; bx = t % 96; by = t / 96; }
        else            { in = w_out; out = woutT; R = 1024; C = 1024; int t = blk - 5376; bx = t % 32; by = t / 32; }
        int c0 = bx * 32, r0 = by * 32;
        int ty = tid >> 3, tx = tid & 7;
        float4 v = *(const float4*)&in[(size_t)(r0 + ty) * C + c0 + tx * 4];
        *(float4*)&tile[ty][tx * 4] = v;
        __syncthreads();
        int cc = tid & 31, rq = tid >> 5;
        float t0 = tile[rq * 4 + 0][cc], t1 = tile[rq * 4 + 1][cc];
        float t2 = tile[rq * 4 + 2][cc], t3 = tile[rq * 4 + 3][cc];
        uint2 w;
        w.x = cvtpk_bf16(t0, t1);
        w.y = cvtpk_bf16(t2, t3);
        *(uint2*)&out[(size_t)(c0 + cc) * R + r0 + rq * 4] = w;
    }
}

// ---------------- GEMM1: qkv = x @ w_qkv + b, fused RoPE on q,k ----------------
// Tile 128x128, BK=128 (8 iters), XOR-swizzled single-buffer LDS (64 KB). (R20-proven, 45.2us)
__global__ __launch_bounds__(256) void gemm_qkv_kernel(const ushort_t* __restrict__ A, const ushort_t* __restrict__ Bt,
                                                       const float* __restrict__ bias, const float2* __restrict__ cstab,
                                                       ushort_t* __restrict__ qw, ushort_t* __restrict__ kw,
                                                       ushort_t* __restrict__ vw) {
    const int K = 1024;
    __shared__ ushort_t As[128 * 128];   // 32 KB
    __shared__ ushort_t Bs[128 * 128];   // 32 KB
    int tid = threadIdx.x, lane = tid & 63, wid = tid >> 6;
    int lm = lane & 15, lg = lane >> 4;
    int bid = blockIdx.x;               // 768 blocks
    int xcd = bid & 7, idx = bid >> 3;  // idx in [0,96)
    int bm = xcd * 4 + idx / 24;
    int bn = idx % 24;
    int wm = wid >> 1, wn = wid & 1;

    int cbase = bn * 128 + wn * 64;     // 64-col band = one head's D
    bool qk = (cbase < 2048);

    f32x4 acc[4][4] = {};
    const ushort_t* ag = A + (size_t)bm * 128 * K;
    const ushort_t* bg = Bt + (size_t)bn * 128 * K;

    for (int kt = 0; kt < K / 128; ++kt) {
        __syncthreads();
#pragma unroll
        for (int c = 0; c < 8; ++c) {
            int G = c * 256 + tid;                      // granule id 0..2047
            int rr = G >> 4;                            // tile row 0..127
            int slot = G & 15;                          // LDS slot 0..15
            int gs = (slot & 8) | ((slot & 7) ^ (rr & 7));
            gload_lds16(ag + (size_t)rr * K + kt * 128 + gs * 8, As + (c * 256 + wid * 64) * 8);
            gload_lds16(bg + (size_t)rr * K + kt * 128 + gs * 8, Bs + (c * 256 + wid * 64) * 8);
        }
        __syncthreads();   // compiler drains vmcnt before barrier
#pragma unroll
        for (int kk = 0; kk < 4; ++kk) {
            bfrag a[4], b[4];
#pragma unroll
            for (int mi = 0; mi < 4; ++mi) {
                int row = wm * 64 + mi * 16 + lm;
                int slot = kk * 4 + lg;
                int phys = (slot & 8) | ((slot & 7) ^ (lm & 7));
                a[mi] = *(const bfrag*)&As[row * 128 + phys * 8];
            }
#pragma unroll
            for (int ni = 0; ni < 4; ++ni) {
                int row = wn * 64 + ni * 16 + lm;
                int slot = kk * 4 + lg;
                int phys = (slot & 8) | ((slot & 7) ^ (lm & 7));
                b[ni] = *(const bfrag*)&Bs[row * 128 + phys * 8];
            }
            if (qk) {
#pragma unroll
                for (int mi = 0; mi < 4; ++mi)
#pragma unroll
                    for (int ni = 0; ni < 4; ++ni)
                        acc[mi][ni] = __builtin_amdgcn_mfma_f32_16x16x32_bf16(b[ni], a[mi], acc[mi][ni], 0, 0, 0);
            } else {
#pragma unroll
                for (int mi = 0; mi < 4; ++mi)
#pragma unroll
                    for (int ni = 0; ni < 4; ++ni)
                        acc[mi][ni] = __builtin_amdgcn_mfma_f32_16x16x32_bf16(a[mi], b[ni], acc[mi][ni], 0, 0, 0);
            }
        }
    }

    int sel = cbase >> 10;                    // 0=q 1=k 2=v
    int h = (cbase & 1023) >> 6;
    if (qk) {
        // swapped layout: acc[mi][ni][i] at (d = ni*16+lg*4+i, t-row = mi*16+lm)
        ushort_t* dst = sel ? kw : qw;
        float scale = sel ? 1.0f : 0.18033688011112042f;  // q: 1/sqrt(64) * log2(e)
        float4 bias4[4];
#pragma unroll
        for (int ni = 0; ni < 4; ++ni)
            bias4[ni] = *(const float4*)&bias[cbase + ni * 16 + lg * 4];
#pragma unroll
        for (int mi = 0; mi < 4; ++mi) {
            int r = bm * 128 + wm * 64 + mi * 16 + lm;
            int bb = r >> 11, t = r & (T_ - 1);
            size_t rowbase = ((size_t)(bb * H_ + h) * T_ + t) * D_;
#pragma unroll
            for (int nip = 0; nip < 2; ++nip) {
                const float4* cs2 = (const float4*)(cstab + t * 32 + nip * 16 + lg * 4);
                float4 ca = cs2[0], cb = cs2[1];   // (c0,s0,c1,s1),(c2,s2,c3,s3)
                float xl[4], xh[4];
#pragma unroll
                for (int i = 0; i < 4; ++i) {
                    xl[i] = acc[mi][nip][i]     + ((const float*)&bias4[nip])[i];
                    xh[i] = acc[mi][nip + 2][i] + ((const float*)&bias4[nip + 2])[i];
                }
                float rl0 = (xl[0] * ca.x - xh[0] * ca.y) * scale;
                float rl1 = (xl[1] * ca.z - xh[1] * ca.w) * scale;
                float rl2 = (xl[2] * cb.x - xh[2] * cb.y) * scale;
                float rl3 = (xl[3] * cb.z - xh[3] * cb.w) * scale;
                float rh0 = (xh[0] * ca.x + xl[0] * ca.y) * scale;
                float rh1 = (xh[1] * ca.z + xl[1] * ca.w) * scale;
                float rh2 = (xh[2] * cb.x + xl[2] * cb.y) * scale;
                float rh3 = (xh[3] * cb.z + xl[3] * cb.w) * scale;
                uint2 wlo, whi;
                wlo.x = cvtpk_bf16(rl0, rl1); wlo.y = cvtpk_bf16(rl2, rl3);
                whi.x = cvtpk_bf16(rh0, rh1); whi.y = cvtpk_bf16(rh2, rh3);
                *(uint2*)&dst[rowbase + nip * 16 + lg * 4]      = wlo;
                *(uint2*)&dst[rowbase + 32 + nip * 16 + lg * 4] = whi;
            }
        }
    } else {
        // normal layout: acc[mi][ni][i] at (t-row = mi*16+lg*4+i, d = ni*16+lm)
        float bb4[4];
#pragma unroll
        for (int ni = 0; ni < 4; ++ni) bb4[ni] = bias[cbase + ni * 16 + lm];
#pragma unroll
        for (int ni = 0; ni < 4; ++ni) {
            int d = ni * 16 + lm;
#pragma unroll
            for (int mi = 0; mi < 4; ++mi) {
                int r = bm * 128 + wm * 64 + mi * 16 + lg * 4;
                int bb = r >> 11, tq = r & (T_ - 1);
                uint2 w;
                w.x = cvtpk_bf16(acc[mi][ni][0] + bb4[ni], acc[mi][ni][1] + bb4[ni]);
                w.y = cvtpk_bf16(acc[mi][ni][2] + bb4[ni], acc[mi][ni][3] + bb4[ni]);
                *(uint2*)&vw[((size_t)(bb * H_ + h) * D_ + d) * T_ + tq] = w;
            }
        }
    }
}

// ---------------- causal flash attention: LDS-shared K/V tiles, 4 waves x 32 Q-rows ----------------
// KVBLK=256 staged once (64 KB), computed as FOUR 64-key quarters (R19-proven; no setprio —
// R22 A/B showed it costs 2.4us in this barrier-synced structure).
__global__ __launch_bounds__(256, 2) void flash_kernel(const ushort_t* __restrict__ q, const ushort_t* __restrict__ k,
                                                       const ushort_t* __restrict__ vt, ushort_t* __restrict__ o) {
    __shared__ ushort_t smemK[256 * 64];   // 32 KB
    __shared__ ushort_t smemV[64 * 256];   // 32 KB
    int tid = threadIdx.x, lane = tid & 63, wid = tid >> 6;
    int lm = lane & 15, lg = lane >> 4;
    int x = blockIdx.x & 7, r = blockIdx.x >> 3;   // x = XCD
    int half = r >> 5, idx = r & 31;
    int bh = x * 4 + (idx & 3);             // XCD x owns bh 4x..4x+3
    int jq = idx >> 2;
    int j = half ? jq : 15 - jq;            // q-block (128 rows); long (j=15) first
    int q0w = j * 128 + wid * 32;           // this wave's 32 rows
    int b = bh >> 4, h = bh & 15;
    int nt = (j >> 1) + 1;                  // 256-key tiles

    const ushort_t* qb = q + (size_t)bh * T_ * D_;
    const ushort_t* kb = k + (size_t)bh * T_ * D_;
    const ushort_t* vb = vt + (size_t)bh * D_ * T_;

    bfrag aq[2][2];
#pragma unroll
    for (int s = 0; s < 2; ++s)
#pragma unroll
        for (int hh = 0; hh < 2; ++hh)
            aq[s][hh] = *(const bfrag*)(qb + (size_t)(q0w + s * 16 + lm) * D_ + hh * 32 + lg * 8);

    f32x4 acc[2][4] = {};
    float lsum[2] = {0.f, 0.f};

    for (int t = 0; t < nt; ++t) {
        int k0 = t * 256;
        __syncthreads();
#pragma unroll
        for (int c = 0; c < 8; ++c) {
            int G = c * 256 + tid;                            // granule 0..2047
            int rrk = G >> 3, gk = (G & 7) ^ (rrk & 7);       // K: 256 rows x 8 granules
            gload_lds16(kb + (size_t)(k0 + rrk) * D_ + gk * 8, smemK + (c * 256 + wid * 64) * 8);
            int rrv = G >> 5, gv = (G & 31) ^ (rrv & 7);      // V: 64 rows x 32 granules
            gload_lds16(vb + (size_t)rrv * T_ + k0 + gv * 8, smemV + (c * 256 + wid * 64) * 8);
        }
        drain_vmem();
        __syncthreads();

        for (int h1 = 0; h1 < 4; ++h1) {
            int hk0 = k0 + h1 * 64;
            if (hk0 > q0w + 31) continue;   // causally dead quarter for this wave
            bfrag ka[4][2];
#pragma unroll
            for (int sb = 0; sb < 4; ++sb)
#pragma unroll
                for (int hh = 0; hh < 2; ++hh) {
                    int krr = h1 * 64 + sb * 16 + lm;
                    int gr = (hh * 4 + lg) ^ (krr & 7);
                    ka[sb][hh] = *(const bfrag*)&smemK[krr * 64 + gr * 8];
                }
            s16x4 vq[4][4];
#pragma unroll
            for (int qq = 0; qq < 4; ++qq)
#pragma unroll
                for (int db = 0; db < 4; ++db) {
                    int rr = db * 16 + lm;
                    int g = h1 * 8 + qq * 2 + (lg >> 1);
                    int p = g ^ (rr & 7);
                    vq[qq][db] = *(const s16x4*)&smemV[rr * 256 + p * 8 + (lg & 1) * 4];
                }
            f32x4 st[2][4];
#pragma unroll
            for (int s = 0; s < 2; ++s)
#pragma unroll
                for (int sb = 0; sb < 4; ++sb) {
                    f32x4 z = {};
                    z = __builtin_amdgcn_mfma_f32_16x16x32_bf16(ka[sb][0], aq[s][0], z, 0, 0, 0);
                    st[s][sb] = __builtin_amdgcn_mfma_f32_16x16x32_bf16(ka[sb][1], aq[s][1], z, 0, 0, 0);
                }
            if (hk0 + 63 > q0w) {
#pragma unroll
                for (int s = 0; s < 2; ++s)
#pragma unroll
                    for (int sb = 0; sb < 4; ++sb)
#pragma unroll
                        for (int i = 0; i < 4; ++i)
                            if (hk0 + sb * 16 + lg * 4 + i > q0w + s * 16 + lm) st[s][sb][i] = -1e30f;
            }
#pragma unroll
            for (int s = 0; s < 2; ++s) {
                float pv[4][4];
#pragma unroll
                for (int sb = 0; sb < 4; ++sb)
#pragma unroll
                    for (int i = 0; i < 4; ++i)
                        pv[sb][i] = EXP2(st[s][sb][i]);
                lsum[s] += ((pv[0][0] + pv[0][1]) + (pv[0][2] + pv[0][3])) +
                           ((pv[1][0] + pv[1][1]) + (pv[1][2] + pv[1][3])) +
                           ((pv[2][0] + pv[2][1]) + (pv[2][2] + pv[2][3])) +
                           ((pv[3][0] + pv[3][1]) + (pv[3][2] + pv[3][3]));
                uint4 u0, u1;
                u0.x = cvtpk_bf16(pv[0][0], pv[0][1]);
                u0.y = cvtpk_bf16(pv[0][2], pv[0][3]);
                u0.z = cvtpk_bf16(pv[1][0], pv[1][1]);
                u0.w = cvtpk_bf16(pv[1][2], pv[1][3]);
                u1.x = cvtpk_bf16(pv[2][0], pv[2][1]);
                u1.y = cvtpk_bf16(pv[2][2], pv[2][3]);
                u1.z = cvtpk_bf16(pv[3][0], pv[3][1]);
                u1.w = cvtpk_bf16(pv[3][2], pv[3][3]);
                bfrag pf0 = __builtin_bit_cast(bfrag, u0);
                bfrag pf1 = __builtin_bit_cast(bfrag, u1);
#pragma unroll
                for (int db = 0; db < 4; ++db) {
                    bfrag va01 = __builtin_shufflevector(vq[0][db], vq[1][db], 0, 1, 2, 3, 4, 5, 6, 7);
                    bfrag va23 = __builtin_shufflevector(vq[2][db], vq[3][db], 0, 1, 2, 3, 4, 5, 6, 7);
                    acc[s][db] = __builtin_amdgcn_mfma_f32_16x16x32_bf16(va01, pf0, acc[s][db], 0, 0, 0);
                    acc[s][db] = __builtin_amdgcn_mfma_f32_16x16x32_bf16(va23, pf1, acc[s][db], 0, 0, 0);
                }
            }
        }
    }

#pragma unroll
    for (int s = 0; s < 2; ++s) {
        float lM = lsum[s];
        lM += __shfl_xor(lM, 16);
        lM += __shfl_xor(lM, 32);
        float inv = 1.0f / lM;
        int tq = q0w + s * 16 + lm;
        size_t ro = ((size_t)b * T_ + tq) * E_ + h * D_;
#pragma unroll
        for (int db = 0; db < 4; ++db) {
            uint2 w;
            w.x = cvtpk_bf16(acc[s][db][0] * inv, acc[s][db][1] * inv);
            w.y = cvtpk_bf16(acc[s][db][2] * inv, acc[s][db][3] * inv);
            *(uint2*)(o + ro + db * 16 + lg * 4) = w;
        }
    }
}

// ---------------- GEMM2: out = ao @ w_out + b_out (fp32 out) ----------------
// Tile 128x64, BK=128 (8 iters), XOR-swizzled SINGLE-buffer LDS (48 KB). (R21-proven)
__global__ __launch_bounds__(256) void gemm_out_kernel(const ushort_t* __restrict__ A, const ushort_t* __restrict__ Bt,
                                                       const float* __restrict__ bias, float* __restrict__ out) {
    const int K = 1024;
    __shared__ ushort_t As[128 * 128];   // 32 KB
    __shared__ ushort_t Bs[64 * 128];    // 16 KB
    int tid = threadIdx.x, lane = tid & 63, wid = tid >> 6;
    int lm = lane & 15, lg = lane >> 4;
    int bid = blockIdx.x;               // 512 blocks
    int xcd = bid & 7, idx = bid >> 3;  // idx in [0,64)
    int bm = xcd * 4 + idx / 16;
    int bn = idx % 16;

    f32x4 acc[2][4] = {};
    const ushort_t* ag = A + (size_t)bm * 128 * K;
    const ushort_t* bg = Bt + (size_t)bn * 64 * K;

    for (int kt = 0; kt < K / 128; ++kt) {
        __syncthreads();
#pragma unroll
        for (int c = 0; c < 8; ++c) {
            int G = c * 256 + tid;                      // granule 0..2047
            int rr = G >> 4;                            // tile row 0..127
            int slot = G & 15;
            int gs = (slot & 8) | ((slot & 7) ^ (rr & 7));
            gload_lds16(ag + (size_t)rr * K + kt * 128 + gs * 8, As + (c * 256 + wid * 64) * 8);
        }
#pragma unroll
        for (int c = 0; c < 4; ++c) {
            int G = c * 256 + tid;                      // granule 0..1023
            int rr = G >> 4;                            // tile row 0..63
            int slot = G & 15;
            int gs = (slot & 8) | ((slot & 7) ^ (rr & 7));
            gload_lds16(bg + (size_t)rr * K + kt * 128 + gs * 8, Bs + (c * 256 + wid * 64) * 8);
        }
        __syncthreads();   // compiler drains vmcnt before barrier
#pragma unroll
        for (int kk = 0; kk < 4; ++kk) {
            bfrag a[2], b[4];
#pragma unroll
            for (int mi = 0; mi < 2; ++mi) {
                int row = wid * 32 + mi * 16 + lm;
                int slot = kk * 4 + lg;
                int phys = (slot & 8) | ((slot & 7) ^ (lm & 7));
                a[mi] = *(const bfrag*)&As[row * 128 + phys * 8];
            }
#pragma unroll
            for (int ni = 0; ni < 4; ++ni) {
                int row = ni * 16 + lm;
                int slot = kk * 4 + lg;
                int phys = (slot & 8) | ((slot & 7) ^ (lm & 7));
                b[ni] = *(const bfrag*)&Bs[row * 128 + phys * 8];
            }
#pragma unroll
            for (int mi = 0; mi < 2; ++mi)
#pragma unroll
                for (int ni = 0; ni < 4; ++ni)
                    acc[mi][ni] = __builtin_amdgcn_mfma_f32_16x16x32_bf16(a[mi], b[ni], acc[mi][ni], 0, 0, 0);
        }
    }

#pragma unroll
    for (int ni = 0; ni < 4; ++ni) {
        int c = bn * 64 + ni * 16 + lm;
        float bb = bias[c];
#pragma unroll
        for (int mi = 0; mi < 2; ++mi) {
#pragma unroll
            for (int i = 0; i < 4; ++i) {
                int r = bm * 128 + wid * 32 + mi * 16 + lg * 4 + i;
                out[(size_t)r * 1024 + c] = acc[mi][ni][i] + bb;
            }
        }
    }
}

extern "C" void kernel_launch(void* const* d_in, const int* in_sizes, int n_in,
                              void* d_out, int out_size, void* d_ws, size_t ws_size,
                              hipStream_t stream) {
    const float* x     = (const float*)d_in[0];
    const float* w_qkv = (const float*)d_in[1];
    const float* b_qkv = (const float*)d_in[2];
    const float* w_out = (const float*)d_in[3];
    const float* b_out = (const float*)d_in[4];
    float* out = (float*)d_out;

    ushort_t* ws    = (ushort_t*)d_ws;
    ushort_t* xb    = ws;                   // [4096][1024] bf16
    ushort_t* wqkvT = xb + 4194304;         // [3072][1024] bf16
    ushort_t* woutT = wqkvT + 3145728;      // [1024][1024] bf16
    ushort_t* qw    = woutT + 1048576;      // [BH][T][D]
    ushort_t* kw    = qw + 4194304;
    ushort_t* vw    = kw + 4194304;         // Vt: [BH][D][T]
    ushort_t* ao    = vw + 4194304;         // [4096][1024] bf16
    float2*   cstab = (float2*)(ao + 4194304);  // [2048][32] (cos,sin) = 512 KB

    prep_kernel<<<dim3(6400), 256, 0, stream>>>(x, w_qkv, w_out, xb, wqkvT, woutT, cstab);
    gemm_qkv_kernel<<<dim3(768), 256, 0, stream>>>(xb, wqkvT, b_qkv, cstab, qw, kw, vw);
    flash_kernel<<<dim3(512), 256, 0, stream>>>(qw, kw, vw, ao);
    gemm_out_kernel<<<dim3(512), 256, 0, stream>>>(ao, woutT, b_out, out);
}